// Round 10
// baseline (198.702 us; speedup 1.0000x reference)
//
#include <hip/hip_runtime.h>

// ---------------------------------------------------------------------------
// CausalSelfAttention, banded (band=256), B=2 T=2048 C=1024 H=16 hd=64.
// cvt(fp32->bf16) -> fused QKV bf16-MFMA GEMM (128x128, BK=32; B staged in
// LDS via global_load_lds, A-frags read DIRECT FROM GLOBAL (L2-hot) to halve
// LDS bandwidth -- r9 analysis: K-loop is LDS-BW-bound, 144KB/CU-iter;
// V written TRANSPOSED [b,h,d,t]) -> banded MFMA flash attention (r6
// known-good) -> output projection GEMM (64x128, same A-direct scheme).
// Workspace layout (bytes):
//   [0,8M)    xb   bf16 [4096,1024]
//   [8M,14M)  wqkv bf16 3x[1024,1024]
//   [14M,16M) wpb  bf16 [1024,1024]
//   [16M,40M) qkv  bf16 q,k:[B,H,T,64], v:[B,H,64,T]
//   [40M,48M) yb   bf16 [4096,1024]
// ---------------------------------------------------------------------------

typedef __attribute__((ext_vector_type(8))) short bf16x8;
typedef __attribute__((ext_vector_type(8))) unsigned short u16x8;
typedef __attribute__((ext_vector_type(4))) float f32x4;

__device__ __forceinline__ float bf2f(unsigned short u) {
  union { unsigned u; float f; } x; x.u = ((unsigned)u) << 16; return x.f;
}
__device__ __forceinline__ unsigned short f2bf(float f) {
  union { float f; unsigned u; } x; x.f = f;
  unsigned r = x.u + 0x7FFFu + ((x.u >> 16) & 1u);  // RNE
  return (unsigned short)(r >> 16);
}

#define GLOAD_LDS16(g, l)                                                     \
  __builtin_amdgcn_global_load_lds(                                           \
      (__attribute__((address_space(1))) void*)(g),                           \
      (__attribute__((address_space(3))) void*)(l), 16, 0, 0)

// ---------------- fp32 -> bf16 (RNE), all 5 tensors in one launch ----------
__global__ void cvt_all(const float* __restrict__ x, const float* __restrict__ Wq,
                        const float* __restrict__ Wk, const float* __restrict__ Wv,
                        const float* __restrict__ Wp, unsigned short* __restrict__ xb,
                        unsigned short* __restrict__ wqkv,
                        unsigned short* __restrict__ wpb) {
  int i = blockIdx.x * 256 + threadIdx.x;  // grid covers exactly 2097152
  const float* src;
  unsigned short* dst;
  int off;
  if (i < 1048576)      { src = x;  dst = xb;             off = i; }
  else if (i < 1310720) { src = Wq; dst = wqkv;           off = i - 1048576; }
  else if (i < 1572864) { src = Wk; dst = wqkv + 1048576; off = i - 1310720; }
  else if (i < 1835008) { src = Wv; dst = wqkv + 2097152; off = i - 1572864; }
  else                  { src = Wp; dst = wpb;            off = i - 1835008; }
  float4 v = ((const float4*)src)[off];
  ushort4 o;
  o.x = f2bf(v.x); o.y = f2bf(v.y); o.z = f2bf(v.z); o.w = f2bf(v.w);
  ((ushort4*)dst)[off] = o;
}

// ---------------- fused QKV bf16 GEMM, 128x128, A-direct-from-global -------
// C[m][n] = sum_k A[m][k]*W[n][k] + bias[n]; BK=32, 4 waves each 64x64.
// B (weights) staged via global_load_lds (8KB/iter); A-frags loaded straight
// from global: global_load_dwordx4 touching 16 rows x one 64B line each,
// L2-hot (each x-row read by 24 blocks). Halves LDS traffic 48->24KB/iter.
// bf16 scatter; proj 0/1 (q/k) -> [b,h,t,d]; proj 2 (v) -> [b,h,d,t].
__global__ __launch_bounds__(256) void gemm_qkv(
    const unsigned short* __restrict__ A, const unsigned short* __restrict__ Wall,
    const float* __restrict__ b0, const float* __restrict__ b1,
    const float* __restrict__ b2, unsigned short* __restrict__ outp) {
  constexpr int K = 1024;
  __shared__ __align__(16) unsigned short Bs[128 * 32];  // 8 KB
  int tid = threadIdx.x;
  int m0 = blockIdx.x * 128;
  int proj = blockIdx.y >> 3;
  int n0 = (blockIdx.y & 7) * 128;
  const unsigned short* W = Wall + (size_t)proj * (K * 1024);
  const float* bias = (proj == 0) ? b0 : ((proj == 1) ? b1 : b2);
  unsigned short* out = outp + (size_t)proj * 4194304;
  int w = tid >> 6, lane = tid & 63;
  int wm = (w >> 1) * 64, wn = (w & 1) * 64;
  int lm = lane & 15, quad = lane >> 4;

  f32x4 acc[4][4];
#pragma unroll
  for (int mi = 0; mi < 4; ++mi)
#pragma unroll
    for (int ni = 0; ni < 4; ++ni) acc[mi][ni] = (f32x4){0.f, 0.f, 0.f, 0.f};

  // B staging: 8KB = 256 thr x 16B x 2
  int o0 = tid * 16, o1 = o0 + 4096;
  int r0 = o0 >> 6, cb0 = o0 & 63;
  int r1 = o1 >> 6, cb1 = o1 & 63;
  const char* w0 = (const char*)W + (size_t)(n0 + r0) * (K * 2) + cb0;
  const char* w1 = (const char*)W + (size_t)(n0 + r1) * (K * 2) + cb1;
  char* lB = (char*)Bs;

  // A-frag base: row m0+wm+mi*16+lm, cols k0+quad*8 .. +8
  const unsigned short* aRow = A + (size_t)(m0 + wm + lm) * K + quad * 8;

  for (int k0 = 0; k0 < K; k0 += 32) {
    GLOAD_LDS16(w0 + k0 * 2, lB + o0);
    GLOAD_LDS16(w1 + k0 * 2, lB + o1);
    __syncthreads();
    bf16x8 af[4], bfv[4];
#pragma unroll
    for (int mi = 0; mi < 4; ++mi)
      af[mi] = *(const bf16x8*)(aRow + (size_t)mi * 16 * K + k0);
#pragma unroll
    for (int ni = 0; ni < 4; ++ni)
      bfv[ni] = *(const bf16x8*)(Bs + (wn + ni * 16 + lm) * 32 + quad * 8);
#pragma unroll
    for (int mi = 0; mi < 4; ++mi)
#pragma unroll
      for (int ni = 0; ni < 4; ++ni)
        acc[mi][ni] = __builtin_amdgcn_mfma_f32_16x16x32_bf16(
            af[mi], bfv[ni], acc[mi][ni], 0, 0, 0);
    __syncthreads();
  }
  // epilogue: C/D layout col=lane&15, row=quad*4+reg
#pragma unroll
  for (int mi = 0; mi < 4; ++mi) {
#pragma unroll
    for (int ni = 0; ni < 4; ++ni) {
      int gn = n0 + wn + ni * 16 + lm;
      float bv = bias[gn];
#pragma unroll
      for (int r = 0; r < 4; ++r) {
        int gm = m0 + wm + mi * 16 + quad * 4 + r;
        float val = acc[mi][ni][r] + bv;
        int bb = gm >> 11, tt = gm & 2047;
        int hh = gn >> 6, dd = gn & 63;
        size_t idx;
        if (proj == 2)  // V transposed: [b,h,d,t]
          idx = (((size_t)bb * 16 + hh) * 64 + dd) * 2048 + tt;
        else            // Q,K: [b,h,t,d]
          idx = (((size_t)bb * 16 + hh) * 2048 + tt) * 64 + dd;
        out[idx] = f2bf(val);
      }
    }
  }
}

// ---------------- output projection GEMM, 64x128, A-direct-from-global -----
__global__ __launch_bounds__(256) void gemm_p64(
    const unsigned short* __restrict__ A, const unsigned short* __restrict__ W,
    const float* __restrict__ bias, float* __restrict__ out) {
  constexpr int K = 1024;
  __shared__ __align__(16) unsigned short Bs[128 * 32];  // 8 KB
  int tid = threadIdx.x;
  int m0 = blockIdx.x * 64, n0 = blockIdx.y * 128;
  int w = tid >> 6, lane = tid & 63;
  int wm = (w >> 1) * 32, wn = (w & 1) * 64;
  int lm = lane & 15, quad = lane >> 4;

  f32x4 acc[2][4];
#pragma unroll
  for (int mi = 0; mi < 2; ++mi)
#pragma unroll
    for (int ni = 0; ni < 4; ++ni) acc[mi][ni] = (f32x4){0.f, 0.f, 0.f, 0.f};

  int o0 = tid * 16, o1 = o0 + 4096;
  int r0 = o0 >> 6, cb0 = o0 & 63;
  int r1 = o1 >> 6, cb1 = o1 & 63;
  const char* w0 = (const char*)W + (size_t)(n0 + r0) * (K * 2) + cb0;
  const char* w1 = (const char*)W + (size_t)(n0 + r1) * (K * 2) + cb1;
  char* lB = (char*)Bs;

  const unsigned short* aRow = A + (size_t)(m0 + wm + lm) * K + quad * 8;

  for (int k0 = 0; k0 < K; k0 += 32) {
    GLOAD_LDS16(w0 + k0 * 2, lB + o0);
    GLOAD_LDS16(w1 + k0 * 2, lB + o1);
    __syncthreads();
    bf16x8 af[2], bfv[4];
#pragma unroll
    for (int mi = 0; mi < 2; ++mi)
      af[mi] = *(const bf16x8*)(aRow + (size_t)mi * 16 * K + k0);
#pragma unroll
    for (int ni = 0; ni < 4; ++ni)
      bfv[ni] = *(const bf16x8*)(Bs + (wn + ni * 16 + lm) * 32 + quad * 8);
#pragma unroll
    for (int mi = 0; mi < 2; ++mi)
#pragma unroll
      for (int ni = 0; ni < 4; ++ni)
        acc[mi][ni] = __builtin_amdgcn_mfma_f32_16x16x32_bf16(
            af[mi], bfv[ni], acc[mi][ni], 0, 0, 0);
    __syncthreads();
  }
#pragma unroll
  for (int mi = 0; mi < 2; ++mi) {
#pragma unroll
    for (int ni = 0; ni < 4; ++ni) {
      int gn = n0 + wn + ni * 16 + lm;
      float bv = bias[gn];
#pragma unroll
      for (int r = 0; r < 4; ++r) {
        int gm = m0 + wm + mi * 16 + quad * 4 + r;
        out[(size_t)gm * 1024 + gn] = acc[mi][ni][r] + bv;
      }
    }
  }
}

// ---------------- banded MFMA flash attention, double-buffered DMA ---------
// (round-6 known-good, ~17 us)
__global__ __launch_bounds__(256) void attn_band_mfma(
    const unsigned short* __restrict__ qb, const unsigned short* __restrict__ kb,
    const unsigned short* __restrict__ vtg, unsigned short* __restrict__ yb) {
  __shared__ __align__(16) unsigned short Kb[2][64 * 72];
  __shared__ __align__(16) unsigned short Vb[2][64 * 72];
  int bid = blockIdx.x;
  int qt = bid & 31, h = (bid >> 5) & 15, b = bid >> 9;
  int q0b = qt * 64;
  int tid = threadIdx.x;
  int lane = tid & 63;
  int w = tid >> 6;
  int m = lane & 15, quad = lane >> 4;
  int wq = w * 16;
  int tq0 = q0b + wq;
  size_t hb = ((size_t)(b * 16 + h)) * (2048 * 64);
  size_t vhb = ((size_t)(b * 16 + h)) * (64 * 2048);
  const char* kgb = (const char*)(kb + hb);    // K rows: 128 B stride
  const char* vgb = (const char*)(vtg + vhb);  // Vt rows: 4096 B stride

  int sA = tid, sB = tid + 256, sC = 512 + (tid & 63);
  int rA = sA / 9, kA = sA - rA * 9;
  int rB = sB / 9, kB = sB - rB * 9;
  int rC = sC / 9, kC = sC - rC * 9;
  int okA = (kA < 8) ? kA : 0, okB = (kB < 8) ? kB : 0, okC = (kC < 8) ? kC : 0;
  int offKA = rA * 128 + okA * 16, offVA = rA * 4096 + okA * 16;
  int offKB = rB * 128 + okB * 16, offVB = rB * 4096 + okB * 16;
  int offKC = rC * 128 + okC * 16, offVC = rC * 4096 + okC * 16;

  int jlo = q0b - 256;
  if (jlo < 0) jlo = 0;

  {
    const char* kg = kgb + (size_t)jlo * 128;
    const char* vg = vgb + (size_t)jlo * 2;
    char* kd = (char*)Kb[0];
    char* vd = (char*)Vb[0];
    GLOAD_LDS16(kg + offKA, kd + sA * 16);
    GLOAD_LDS16(kg + offKB, kd + sB * 16);
    GLOAD_LDS16(vg + offVA, vd + sA * 16);
    GLOAD_LDS16(vg + offVB, vd + sB * 16);
    if (tid < 128) {
      const char* g = (tid < 64) ? (kg + offKC) : (vg + offVC);
      char* l = ((tid < 64) ? kd : vd) + sC * 16;
      GLOAD_LDS16(g, l);
    }
  }

  const unsigned short* qrow = qb + hb + (size_t)(tq0 + m) * 64;
  bf16x8 af0 = *(const bf16x8*)(qrow + quad * 8);
  bf16x8 af1 = *(const bf16x8*)(qrow + 32 + quad * 8);

  f32x4 oacc[4];
#pragma unroll
  for (int di = 0; di < 4; ++di) oacc[di] = (f32x4){0.f, 0.f, 0.f, 0.f};
  float lpart[4] = {0.f, 0.f, 0.f, 0.f};

  int cur = 0;
  for (int c0 = jlo; c0 <= q0b; c0 += 64, cur ^= 1) {
    __syncthreads();  // chunk c0 resident (drains its DMA)
    const unsigned short* Kc = Kb[cur];
    const unsigned short* Vc = Vb[cur];
    f32x4 sacc[4];
#pragma unroll
    for (int ni = 0; ni < 4; ++ni) sacc[ni] = (f32x4){0.f, 0.f, 0.f, 0.f};
#pragma unroll
    for (int ni = 0; ni < 4; ++ni) {
      bf16x8 k0 = *(const bf16x8*)(Kc + (ni * 16 + m) * 72 + quad * 8);
      bf16x8 k1 = *(const bf16x8*)(Kc + (ni * 16 + m) * 72 + 32 + quad * 8);
      sacc[ni] = __builtin_amdgcn_mfma_f32_16x16x32_bf16(af0, k0, sacc[ni], 0, 0, 0);
      sacc[ni] = __builtin_amdgcn_mfma_f32_16x16x32_bf16(af1, k1, sacc[ni], 0, 0, 0);
    }
    __syncthreads();  // all waves done reading Kc -> safe to reuse for P
    if (c0 < q0b) {
      const char* kg = kgb + (size_t)(c0 + 64) * 128;
      const char* vg = vgb + (size_t)(c0 + 64) * 2;
      char* kd = (char*)Kb[cur ^ 1];
      char* vd = (char*)Vb[cur ^ 1];
      GLOAD_LDS16(kg + offKA, kd + sA * 16);
      GLOAD_LDS16(kg + offKB, kd + sB * 16);
      GLOAD_LDS16(vg + offVA, vd + sA * 16);
      GLOAD_LDS16(vg + offVB, vd + sB * 16);
      if (tid < 128) {
        const char* g = (tid < 64) ? (kg + offKC) : (vg + offVC);
        char* l = ((tid < 64) ? kd : vd) + sC * 16;
        GLOAD_LDS16(g, l);
      }
    }
    unsigned short* Pw = (unsigned short*)Kc;
#pragma unroll
    for (int ni = 0; ni < 4; ++ni) {
      int j = c0 + ni * 16 + m;
#pragma unroll
      for (int r = 0; r < 4; ++r) {
        int t = tq0 + quad * 4 + r;
        float e = __expf(sacc[ni][r] * 0.125f);
        e = ((unsigned)(t - j) <= 256u) ? e : 0.f;  // causal + band
        lpart[r] += e;
        Pw[(wq + quad * 4 + r) * 72 + ni * 16 + m] = f2bf(e);
      }
    }
#pragma unroll
    for (int ks = 0; ks < 2; ++ks) {
      bf16x8 a = *(const bf16x8*)(Pw + (wq + m) * 72 + ks * 32 + quad * 8);
#pragma unroll
      for (int di = 0; di < 4; ++di) {
        bf16x8 vfr = *(const bf16x8*)(Vc + (di * 16 + m) * 72 + ks * 32 + quad * 8);
        oacc[di] = __builtin_amdgcn_mfma_f32_16x16x32_bf16(a, vfr, oacc[di], 0, 0, 0);
      }
    }
  }
#pragma unroll
  for (int mask = 1; mask <= 8; mask <<= 1)
#pragma unroll
    for (int r = 0; r < 4; ++r) lpart[r] += __shfl_xor(lpart[r], mask, 64);
  float inv[4];
#pragma unroll
  for (int r = 0; r < 4; ++r) inv[r] = 1.f / lpart[r];
  unsigned short* R = &Kb[0][0];
#pragma unroll
  for (int di = 0; di < 4; ++di)
#pragma unroll
    for (int r = 0; r < 4; ++r)
      R[(wq + quad * 4 + r) * 72 + di * 16 + m] = f2bf(oacc[di][r] * inv[r]);
  size_t orow = (size_t)b * 2048 + tq0;
#pragma unroll
  for (int v2 = 0; v2 < 2; ++v2) {
    int v = v2 * 64 + lane;
    int q = v >> 3, dg = v & 7;
    u16x8 val = *(const u16x8*)(R + (wq + q) * 72 + dg * 8);
    *(u16x8*)(yb + (orow + q) * 1024 + h * 64 + dg * 8) = val;
  }
}

// ---------------------------------------------------------------------------
extern "C" void kernel_launch(void* const* d_in, const int* in_sizes, int n_in,
                              void* d_out, int out_size, void* d_ws,
                              size_t ws_size, hipStream_t stream) {
  const float* x  = (const float*)d_in[0];
  const float* Wq = (const float*)d_in[1];
  const float* bq = (const float*)d_in[2];
  const float* Wk = (const float*)d_in[3];
  const float* bk = (const float*)d_in[4];
  const float* Wv = (const float*)d_in[5];
  const float* bv = (const float*)d_in[6];
  const float* Wp = (const float*)d_in[7];
  const float* bp = (const float*)d_in[8];
  float* out = (float*)d_out;

  char* ws = (char*)d_ws;
  unsigned short* xb   = (unsigned short*)(ws);
  unsigned short* wqkv = (unsigned short*)(ws + (8ull << 20));
  unsigned short* wpb  = (unsigned short*)(ws + (14ull << 20));
  unsigned short* qkv  = (unsigned short*)(ws + (16ull << 20));
  unsigned short* yb   = (unsigned short*)(ws + (40ull << 20));

  cvt_all<<<8192, 256, 0, stream>>>(x, Wq, Wk, Wv, Wp, xb, wqkv, wpb);
  gemm_qkv<<<dim3(32, 24), 256, 0, stream>>>(xb, wqkv, bq, bk, bv, qkv);
  attn_band_mfma<<<1024, 256, 0, stream>>>(qkv, qkv + 4194304ull,
                                           qkv + 8388608ull, yb);
  gemm_p64<<<dim3(64, 8), 256, 0, stream>>>(yb, wpb, bp, out);
}

// Round 11
// 167.684 us; speedup vs baseline: 1.1850x; 1.1850x over previous
//
#include <hip/hip_runtime.h>

// ---------------------------------------------------------------------------
// CausalSelfAttention, banded (band=256), B=2 T=2048 C=1024 H=16 hd=64.
// cvt(fp32->bf16) -> fused QKV bf16-MFMA GEMM (r6 known-good m97 structure,
// 128x128 BK=32; V written TRANSPOSED [b,h,d,t]) -> banded MFMA flash attn
// (Tq=128: 4 waves x 32 queries as 2x16-row m-tiles; K/V frags reused across
// m-tiles -> 45% fewer LDS reads, 40% less chunk-DMA, half the barriers) ->
// output projection GEMM (r6 64x128).
// GEMM lesson (r3,r7,r8,r9,r10): six structural variants all lose to the
// plain m97 structure at this shape — do not touch gemm_qkv again.
// Workspace layout (bytes):
//   [0,8M)    xb   bf16 [4096,1024]
//   [8M,14M)  wqkv bf16 3x[1024,1024]
//   [14M,16M) wpb  bf16 [1024,1024]
//   [16M,40M) qkv  bf16 q,k:[B,H,T,64], v:[B,H,64,T]
//   [40M,48M) yb   bf16 [4096,1024]
// ---------------------------------------------------------------------------

typedef __attribute__((ext_vector_type(8))) short bf16x8;
typedef __attribute__((ext_vector_type(8))) unsigned short u16x8;
typedef __attribute__((ext_vector_type(4))) float f32x4;

__device__ __forceinline__ float bf2f(unsigned short u) {
  union { unsigned u; float f; } x; x.u = ((unsigned)u) << 16; return x.f;
}
__device__ __forceinline__ unsigned short f2bf(float f) {
  union { float f; unsigned u; } x; x.f = f;
  unsigned r = x.u + 0x7FFFu + ((x.u >> 16) & 1u);  // RNE
  return (unsigned short)(r >> 16);
}

#define GLOAD_LDS16(g, l)                                                     \
  __builtin_amdgcn_global_load_lds(                                           \
      (__attribute__((address_space(1))) void*)(g),                           \
      (__attribute__((address_space(3))) void*)(l), 16, 0, 0)

// ---------------- fp32 -> bf16 (RNE), all 5 tensors in one launch ----------
__global__ void cvt_all(const float* __restrict__ x, const float* __restrict__ Wq,
                        const float* __restrict__ Wk, const float* __restrict__ Wv,
                        const float* __restrict__ Wp, unsigned short* __restrict__ xb,
                        unsigned short* __restrict__ wqkv,
                        unsigned short* __restrict__ wpb) {
  int i = blockIdx.x * 256 + threadIdx.x;  // grid covers exactly 2097152
  const float* src;
  unsigned short* dst;
  int off;
  if (i < 1048576)      { src = x;  dst = xb;             off = i; }
  else if (i < 1310720) { src = Wq; dst = wqkv;           off = i - 1048576; }
  else if (i < 1572864) { src = Wk; dst = wqkv + 1048576; off = i - 1310720; }
  else if (i < 1835008) { src = Wv; dst = wqkv + 2097152; off = i - 1572864; }
  else                  { src = Wp; dst = wpb;            off = i - 1835008; }
  float4 v = ((const float4*)src)[off];
  ushort4 o;
  o.x = f2bf(v.x); o.y = f2bf(v.y); o.z = f2bf(v.z); o.w = f2bf(v.w);
  ((ushort4*)dst)[off] = o;
}

// ---------------- fused QKV bf16 GEMM (r6 known-good, 42us) ----------------
__global__ __launch_bounds__(256) void gemm_qkv(
    const unsigned short* __restrict__ A, const unsigned short* __restrict__ Wall,
    const float* __restrict__ b0, const float* __restrict__ b1,
    const float* __restrict__ b2, unsigned short* __restrict__ outp) {
  constexpr int K = 1024;
  __shared__ __align__(16) unsigned short As[128 * 32];
  __shared__ __align__(16) unsigned short Bs[128 * 32];
  int tid = threadIdx.x;
  int m0 = blockIdx.x * 128;
  int proj = blockIdx.y >> 3;
  int n0 = (blockIdx.y & 7) * 128;
  const unsigned short* W = Wall + (size_t)proj * (K * 1024);
  const float* bias = (proj == 0) ? b0 : ((proj == 1) ? b1 : b2);
  unsigned short* out = outp + (size_t)proj * 4194304;
  int w = tid >> 6, lane = tid & 63;
  int wm = (w >> 1) * 64, wn = (w & 1) * 64;
  int lm = lane & 15, quad = lane >> 4;

  f32x4 acc[4][4];
#pragma unroll
  for (int mi = 0; mi < 4; ++mi)
#pragma unroll
    for (int ni = 0; ni < 4; ++ni) acc[mi][ni] = (f32x4){0.f, 0.f, 0.f, 0.f};

  int o0 = tid * 16, o1 = o0 + 4096;
  int r0 = o0 >> 6, cb0 = o0 & 63;
  int r1 = o1 >> 6, cb1 = o1 & 63;
  const char* a0 = (const char*)A + (size_t)(m0 + r0) * (K * 2) + cb0;
  const char* a1 = (const char*)A + (size_t)(m0 + r1) * (K * 2) + cb1;
  const char* w0 = (const char*)W + (size_t)(n0 + r0) * (K * 2) + cb0;
  const char* w1 = (const char*)W + (size_t)(n0 + r1) * (K * 2) + cb1;
  char* lA = (char*)As;
  char* lB = (char*)Bs;

  for (int k0 = 0; k0 < K; k0 += 32) {
    GLOAD_LDS16(a0 + k0 * 2, lA + o0);
    GLOAD_LDS16(a1 + k0 * 2, lA + o1);
    GLOAD_LDS16(w0 + k0 * 2, lB + o0);
    GLOAD_LDS16(w1 + k0 * 2, lB + o1);
    __syncthreads();
    bf16x8 af[4], bfv[4];
#pragma unroll
    for (int mi = 0; mi < 4; ++mi)
      af[mi] = *(const bf16x8*)(As + (wm + mi * 16 + lm) * 32 + quad * 8);
#pragma unroll
    for (int ni = 0; ni < 4; ++ni)
      bfv[ni] = *(const bf16x8*)(Bs + (wn + ni * 16 + lm) * 32 + quad * 8);
#pragma unroll
    for (int mi = 0; mi < 4; ++mi)
#pragma unroll
      for (int ni = 0; ni < 4; ++ni)
        acc[mi][ni] = __builtin_amdgcn_mfma_f32_16x16x32_bf16(
            af[mi], bfv[ni], acc[mi][ni], 0, 0, 0);
    __syncthreads();
  }
  // epilogue: C/D layout col=lane&15, row=quad*4+reg
#pragma unroll
  for (int mi = 0; mi < 4; ++mi) {
#pragma unroll
    for (int ni = 0; ni < 4; ++ni) {
      int gn = n0 + wn + ni * 16 + lm;
      float bv = bias[gn];
#pragma unroll
      for (int r = 0; r < 4; ++r) {
        int gm = m0 + wm + mi * 16 + quad * 4 + r;
        float val = acc[mi][ni][r] + bv;
        int bb = gm >> 11, tt = gm & 2047;
        int hh = gn >> 6, dd = gn & 63;
        size_t idx;
        if (proj == 2)  // V transposed: [b,h,d,t]
          idx = (((size_t)bb * 16 + hh) * 64 + dd) * 2048 + tt;
        else            // Q,K: [b,h,t,d]
          idx = (((size_t)bb * 16 + hh) * 2048 + tt) * 64 + dd;
        out[idx] = f2bf(val);
      }
    }
  }
}

// ---------------- output projection GEMM, BM=64 (r6 known-good) ------------
__global__ __launch_bounds__(256) void gemm_p64(
    const unsigned short* __restrict__ A, const unsigned short* __restrict__ W,
    const float* __restrict__ bias, float* __restrict__ out) {
  constexpr int K = 1024;
  __shared__ __align__(16) unsigned short As[64 * 32];   // 4 KB
  __shared__ __align__(16) unsigned short Bs[128 * 32];  // 8 KB
  int tid = threadIdx.x;
  int m0 = blockIdx.x * 64, n0 = blockIdx.y * 128;
  int w = tid >> 6, lane = tid & 63;
  int wm = (w >> 1) * 32, wn = (w & 1) * 64;
  int lm = lane & 15, quad = lane >> 4;

  f32x4 acc[2][4];
#pragma unroll
  for (int mi = 0; mi < 2; ++mi)
#pragma unroll
    for (int ni = 0; ni < 4; ++ni) acc[mi][ni] = (f32x4){0.f, 0.f, 0.f, 0.f};

  int o0 = tid * 16, o1 = o0 + 4096;
  int r0 = o0 >> 6, cb0 = o0 & 63;
  int r1 = o1 >> 6, cb1 = o1 & 63;
  const char* ag = (const char*)A + (size_t)(m0 + r0) * (K * 2) + cb0;
  const char* w0 = (const char*)W + (size_t)(n0 + r0) * (K * 2) + cb0;
  const char* w1 = (const char*)W + (size_t)(n0 + r1) * (K * 2) + cb1;
  char* lA = (char*)As;
  char* lB = (char*)Bs;

  for (int k0 = 0; k0 < K; k0 += 32) {
    GLOAD_LDS16(ag + k0 * 2, lA + o0);
    GLOAD_LDS16(w0 + k0 * 2, lB + o0);
    GLOAD_LDS16(w1 + k0 * 2, lB + o1);
    __syncthreads();
    bf16x8 af[2], bfv[4];
#pragma unroll
    for (int mi = 0; mi < 2; ++mi)
      af[mi] = *(const bf16x8*)(As + (wm + mi * 16 + lm) * 32 + quad * 8);
#pragma unroll
    for (int ni = 0; ni < 4; ++ni)
      bfv[ni] = *(const bf16x8*)(Bs + (wn + ni * 16 + lm) * 32 + quad * 8);
#pragma unroll
    for (int mi = 0; mi < 2; ++mi)
#pragma unroll
      for (int ni = 0; ni < 4; ++ni)
        acc[mi][ni] = __builtin_amdgcn_mfma_f32_16x16x32_bf16(
            af[mi], bfv[ni], acc[mi][ni], 0, 0, 0);
    __syncthreads();
  }
#pragma unroll
  for (int mi = 0; mi < 2; ++mi) {
#pragma unroll
    for (int ni = 0; ni < 4; ++ni) {
      int gn = n0 + wn + ni * 16 + lm;
      float bv = bias[gn];
#pragma unroll
      for (int r = 0; r < 4; ++r) {
        int gm = m0 + wm + mi * 16 + quad * 4 + r;
        out[(size_t)gm * 1024 + gn] = acc[mi][ni][r] + bv;
      }
    }
  }
}

// ---------------- banded MFMA flash attention, Tq=128 ----------------------
// 1 block = 128 queries, 4 waves x 32 queries (2 m-tiles of 16, verified
// 16x16x32 layouts). K/V B-frags read once per chunk, reused across both
// m-tiles (20 b128/wave-chunk vs 36 per 32q in the Tq=64 version). Chunks
// per block <= 6 (keys [q0-256, q0+127]); half the blocks -> 40% less DMA,
// half the barriers. P rows: waves 0-1 -> dead K buffer, waves 2-3 -> Pe.
__global__ __launch_bounds__(256) void attn_band_mfma(
    const unsigned short* __restrict__ qb, const unsigned short* __restrict__ kb,
    const unsigned short* __restrict__ vtg, unsigned short* __restrict__ yb) {
  __shared__ __align__(16) unsigned short Kb[2][64 * 72];
  __shared__ __align__(16) unsigned short Vb[2][64 * 72];
  __shared__ __align__(16) unsigned short Pe[64 * 72];
  int bid = blockIdx.x;  // 512 blocks: 16 qt x 16 h x 2 b
  int qt = bid & 15, h = (bid >> 4) & 15, b = bid >> 8;
  int q0b = qt * 128;
  int tid = threadIdx.x;
  int lane = tid & 63;
  int w = tid >> 6;
  int m = lane & 15, quad = lane >> 4;
  int wq = w * 32;          // wave's first local q row
  int tq0 = q0b + wq;
  size_t hb = ((size_t)(b * 16 + h)) * (2048 * 64);
  size_t vhb = ((size_t)(b * 16 + h)) * (64 * 2048);
  const char* kgb = (const char*)(kb + hb);    // K rows: 128 B stride
  const char* vgb = (const char*)(vtg + vhb);  // Vt rows: 4096 B stride

  // DMA slots: 0..575 = 64 rows x 9 x 16B; slot%9==8 is pad (addr->row base).
  int sA = tid, sB = tid + 256, sC = 512 + (tid & 63);
  int rA = sA / 9, kA = sA - rA * 9;
  int rB = sB / 9, kB = sB - rB * 9;
  int rC = sC / 9, kC = sC - rC * 9;
  int okA = (kA < 8) ? kA : 0, okB = (kB < 8) ? kB : 0, okC = (kC < 8) ? kC : 0;
  int offKA = rA * 128 + okA * 16, offVA = rA * 4096 + okA * 16;
  int offKB = rB * 128 + okB * 16, offVB = rB * 4096 + okB * 16;
  int offKC = rC * 128 + okC * 16, offVC = rC * 4096 + okC * 16;

  int jlo = q0b - 256;
  if (jlo < 0) jlo = 0;
  int cend = q0b + 64;  // last chunk base (keys up to q0b+127)

  // prologue DMA: chunk jlo -> buffers[0]
  {
    const char* kg = kgb + (size_t)jlo * 128;
    const char* vg = vgb + (size_t)jlo * 2;
    char* kd = (char*)Kb[0];
    char* vd = (char*)Vb[0];
    GLOAD_LDS16(kg + offKA, kd + sA * 16);
    GLOAD_LDS16(kg + offKB, kd + sB * 16);
    GLOAD_LDS16(vg + offVA, vd + sA * 16);
    GLOAD_LDS16(vg + offVB, vd + sB * 16);
    if (tid < 128) {
      const char* g = (tid < 64) ? (kg + offKC) : (vg + offVC);
      char* l = ((tid < 64) ? kd : vd) + sC * 16;
      GLOAD_LDS16(g, l);
    }
  }

  // Q A-frags: 2 m-tiles x 2 k-slabs, held all kernel
  bf16x8 af[2][2];
#pragma unroll
  for (int mt = 0; mt < 2; ++mt) {
    const unsigned short* qrow = qb + hb + (size_t)(tq0 + mt * 16 + m) * 64;
    af[mt][0] = *(const bf16x8*)(qrow + quad * 8);
    af[mt][1] = *(const bf16x8*)(qrow + 32 + quad * 8);
  }

  f32x4 oacc[2][4];
#pragma unroll
  for (int mt = 0; mt < 2; ++mt)
#pragma unroll
    for (int di = 0; di < 4; ++di) oacc[mt][di] = (f32x4){0.f, 0.f, 0.f, 0.f};
  float lpart[2][4] = {{0.f, 0.f, 0.f, 0.f}, {0.f, 0.f, 0.f, 0.f}};

  int cur = 0;
  for (int c0 = jlo; c0 <= cend; c0 += 64, cur ^= 1) {
    __syncthreads();  // chunk c0 resident
    const unsigned short* Kc = Kb[cur];
    const unsigned short* Vc = Vb[cur];
    // ---- S = Q K^T: K-frags read once, used by both m-tiles ---------------
    f32x4 sacc[2][4];
#pragma unroll
    for (int mt = 0; mt < 2; ++mt)
#pragma unroll
      for (int ni = 0; ni < 4; ++ni) sacc[mt][ni] = (f32x4){0.f, 0.f, 0.f, 0.f};
#pragma unroll
    for (int ni = 0; ni < 4; ++ni) {
      bf16x8 k0 = *(const bf16x8*)(Kc + (ni * 16 + m) * 72 + quad * 8);
      bf16x8 k1 = *(const bf16x8*)(Kc + (ni * 16 + m) * 72 + 32 + quad * 8);
#pragma unroll
      for (int mt = 0; mt < 2; ++mt) {
        sacc[mt][ni] =
            __builtin_amdgcn_mfma_f32_16x16x32_bf16(af[mt][0], k0, sacc[mt][ni], 0, 0, 0);
        sacc[mt][ni] =
            __builtin_amdgcn_mfma_f32_16x16x32_bf16(af[mt][1], k1, sacc[mt][ni], 0, 0, 0);
      }
    }
    __syncthreads();  // all waves done reading Kc -> safe to reuse for P
    // ---- issue next-chunk DMA (overlaps softmax + PV) ---------------------
    if (c0 < cend) {
      const char* kg = kgb + (size_t)(c0 + 64) * 128;
      const char* vg = vgb + (size_t)(c0 + 64) * 2;
      char* kd = (char*)Kb[cur ^ 1];
      char* vd = (char*)Vb[cur ^ 1];
      GLOAD_LDS16(kg + offKA, kd + sA * 16);
      GLOAD_LDS16(kg + offKB, kd + sB * 16);
      GLOAD_LDS16(vg + offVA, vd + sA * 16);
      GLOAD_LDS16(vg + offVB, vd + sB * 16);
      if (tid < 128) {
        const char* g = (tid < 64) ? (kg + offKC) : (vg + offVC);
        char* l = ((tid < 64) ? kd : vd) + sC * 16;
        GLOAD_LDS16(g, l);
      }
    }
    // ---- softmax piece: P rows: waves 0-1 -> dead Kc, waves 2-3 -> Pe -----
    unsigned short* Pbase =
        (w < 2) ? (unsigned short*)Kc : (unsigned short*)Pe;
    int prow0 = (w < 2) ? wq : (wq - 64);  // wave's first row within region
#pragma unroll
    for (int mt = 0; mt < 2; ++mt) {
#pragma unroll
      for (int ni = 0; ni < 4; ++ni) {
        int j = c0 + ni * 16 + m;
#pragma unroll
        for (int r = 0; r < 4; ++r) {
          int t = tq0 + mt * 16 + quad * 4 + r;
          float e = __expf(sacc[mt][ni][r] * 0.125f);
          e = ((unsigned)(t - j) <= 256u) ? e : 0.f;  // causal + band
          lpart[mt][r] += e;
          Pbase[(prow0 + mt * 16 + quad * 4 + r) * 72 + ni * 16 + m] = f2bf(e);
        }
      }
    }
    // ---- O += P V: V-frags read once, used by both m-tiles ----------------
#pragma unroll
    for (int ks = 0; ks < 2; ++ks) {
      bf16x8 a0 = *(const bf16x8*)(Pbase + (prow0 + m) * 72 + ks * 32 + quad * 8);
      bf16x8 a1 =
          *(const bf16x8*)(Pbase + (prow0 + 16 + m) * 72 + ks * 32 + quad * 8);
#pragma unroll
      for (int di = 0; di < 4; ++di) {
        bf16x8 vfr = *(const bf16x8*)(Vc + (di * 16 + m) * 72 + ks * 32 + quad * 8);
        oacc[0][di] = __builtin_amdgcn_mfma_f32_16x16x32_bf16(a0, vfr, oacc[0][di], 0, 0, 0);
        oacc[1][di] = __builtin_amdgcn_mfma_f32_16x16x32_bf16(a1, vfr, oacc[1][di], 0, 0, 0);
      }
    }
  }
  // ---- finalize -----------------------------------------------------------
#pragma unroll
  for (int mask = 1; mask <= 8; mask <<= 1)
#pragma unroll
    for (int mt = 0; mt < 2; ++mt)
#pragma unroll
      for (int r = 0; r < 4; ++r) lpart[mt][r] += __shfl_xor(lpart[mt][r], mask, 64);
  float inv[2][4];
#pragma unroll
  for (int mt = 0; mt < 2; ++mt)
#pragma unroll
    for (int r = 0; r < 4; ++r) inv[mt][r] = 1.f / lpart[mt][r];
  // scatter normalized O into fixed per-wave regions (waves 0-1: Kb[0],
  // waves 2-3: Pe — disjoint; own-P aliasing is wave-local and ordered)
  unsigned short* Rbase = (w < 2) ? (unsigned short*)Kb[0] : (unsigned short*)Pe;
  int rrow0 = (w < 2) ? wq : (wq - 64);
#pragma unroll
  for (int mt = 0; mt < 2; ++mt)
#pragma unroll
    for (int di = 0; di < 4; ++di)
#pragma unroll
      for (int r = 0; r < 4; ++r)
        Rbase[(rrow0 + mt * 16 + quad * 4 + r) * 72 + di * 16 + m] =
            f2bf(oacc[mt][di][r] * inv[mt][r]);
  __syncthreads();
  // coalesced store: 128 rows x 64 d = 1024 16B-vectors, 4 per thread
  size_t orow = (size_t)b * 2048 + q0b;
#pragma unroll
  for (int it = 0; it < 4; ++it) {
    int v = it * 256 + tid;
    int q = v >> 3, dg = v & 7;
    const unsigned short* src =
        (q < 64) ? (const unsigned short*)Kb[0] : (const unsigned short*)Pe;
    u16x8 val = *(const u16x8*)(src + (q & 63) * 72 + dg * 8);
    *(u16x8*)(yb + (orow + q) * 1024 + h * 64 + dg * 8) = val;
  }
}

// ---------------------------------------------------------------------------
extern "C" void kernel_launch(void* const* d_in, const int* in_sizes, int n_in,
                              void* d_out, int out_size, void* d_ws,
                              size_t ws_size, hipStream_t stream) {
  const float* x  = (const float*)d_in[0];
  const float* Wq = (const float*)d_in[1];
  const float* bq = (const float*)d_in[2];
  const float* Wk = (const float*)d_in[3];
  const float* bk = (const float*)d_in[4];
  const float* Wv = (const float*)d_in[5];
  const float* bv = (const float*)d_in[6];
  const float* Wp = (const float*)d_in[7];
  const float* bp = (const float*)d_in[8];
  float* out = (float*)d_out;

  char* ws = (char*)d_ws;
  unsigned short* xb   = (unsigned short*)(ws);
  unsigned short* wqkv = (unsigned short*)(ws + (8ull << 20));
  unsigned short* wpb  = (unsigned short*)(ws + (14ull << 20));
  unsigned short* qkv  = (unsigned short*)(ws + (16ull << 20));
  unsigned short* yb   = (unsigned short*)(ws + (40ull << 20));

  cvt_all<<<8192, 256, 0, stream>>>(x, Wq, Wk, Wv, Wp, xb, wqkv, wpb);
  gemm_qkv<<<dim3(32, 24), 256, 0, stream>>>(xb, wqkv, bq, bk, bv, qkv);
  attn_band_mfma<<<512, 256, 0, stream>>>(qkv, qkv + 4194304ull,
                                          qkv + 8388608ull, yb);
  gemm_p64<<<dim3(64, 8), 256, 0, stream>>>(yb, wpb, bp, out);
}